// Round 6
// baseline (9286.031 us; speedup 1.0000x reference)
//
#include <hip/hip_runtime.h>
#include <hip/hip_bf16.h>

// EntityAwareLSTMLayer: B=1024, T=365, DYN=32, STATIC=27, U=256 (3U=768)
// Round 6: 4-way N-split across WGs -> per-wave weight slice small enough for
// REAL register residency.
//   - 256 WGs x 256 thr: blockIdx = grp (0..63, 16 batch rows) + 64*slice (0..3).
//   - Wave wv owns units slice*64 + wv*16 .. +15, ALL 3 gates: 27 B-frags =
//     108 VGPRs, pinned via asm("+v") under launch_bounds(256,1) (512 budget).
//   - M=16: full 16x16 C tile, lane = (unit mm, rows qq*4+r): cell state
//     (c, fp32 h identity term, i_gate) in registers, no shuffles.
//   - Per step the 4 WGs of a group exchange h slices (bf16, packed dwords)
//     through d_ws with agent-scope atomics + monotonic arrival counter,
//     double-buffered by step parity. Group members {g,g+64,g+128,g+192} are
//     congruent mod 8 -> same XCD under round-robin dispatch (perf only;
//     correctness from agent-scope atomics). No deadlock: each WG needs
//     <= half a CU, so all 256 WGs are resident under any placement.

typedef short short8 __attribute__((ext_vector_type(8)));
typedef float f32x4 __attribute__((ext_vector_type(4)));

#define T_STEPS 365
#define UNITS   256
#define G3      768
#define KTOT    288
#define MROWS   16
#define NGRP    64
#define AP      296                 // A row length in shorts (592 B, 16B-aligned)
#define WP_BYTES (KTOT * G3 * 2)    // 442368
#define CNT_OFF  WP_BYTES           // 64 uint counters
#define EXCH_OFF (WP_BYTES + 1024)  // exchange: 2*64*4*512 dwords = 1 MB

__device__ __forceinline__ unsigned short f2bf(float x) {
    union { float f; unsigned u; } v; v.f = x;
    return (unsigned short)((v.u + 0x7FFFu + ((v.u >> 16) & 1u)) >> 16);
}
__device__ __forceinline__ float sigmoidf_(float x) {
    return 1.0f / (1.0f + __expf(-x));
}
__device__ __forceinline__ float tanhf_(float x) {
    return 1.0f - 2.0f / (1.0f + __expf(2.0f * x));
}

// Wpack[k=0..287][n=0..767] -> bf16 B-frag layout: wp[((k>>3)*768 + n)*8 + (k&7)]
__global__ __launch_bounds__(256) void pack_weights(
    const float* __restrict__ w_ih, const float* __restrict__ w_hh,
    unsigned short* __restrict__ wp)
{
    int idx = blockIdx.x * 256 + threadIdx.x;
    if (idx >= KTOT * G3) return;
    int k = idx / G3, n = idx - k * G3;
    float v;
    if (k < UNITS) {
        v = w_hh[k * G3 + n];
        if ((n & 255) == k) v -= 1.0f;   // subtract eye3 tile
    } else {
        v = w_ih[(k - UNITS) * G3 + n];
    }
    wp[(((k >> 3) * G3) + n) * 8 + (k & 7)] = f2bf(v);
}

__global__ __launch_bounds__(256, 1) void lstm_nsplit(
    const float* __restrict__ x_dyn,   // [1024][365][32]
    const float* __restrict__ x_sta,   // [1024][27]
    const unsigned short* __restrict__ wp,
    const float* __restrict__ w_sh,    // [27][256]
    const float* __restrict__ bias,    // [768]
    const float* __restrict__ bias_s,  // [256]
    unsigned int* __restrict__ cnt,    // [64] arrival counters (zeroed)
    unsigned int* __restrict__ exch,   // [2][64][4][512] packed bf16 h pairs
    float* __restrict__ out)           // [1024][256]
{
    __shared__ unsigned short A_s[2][MROWS][AP];   // [h(0..255) | x(256..287)]

    const int tid  = threadIdx.x;
    const int grp  = blockIdx.x & 63;
    const int sl   = blockIdx.x >> 6;          // N-slice 0..3
    const int b0   = grp * MROWS;
    const int lane = tid & 63;
    const int wv   = tid >> 6;                 // wave 0..3
    const int mm   = lane & 15;
    const int qq   = lane >> 4;
    const int u    = sl * 64 + wv * 16 + mm;   // global unit this lane owns

    // ---- 27 B-fragments (9 ksteps x 3 gates), pinned resident ----
    short8 bw[9][3];
    #pragma unroll
    for (int ks = 0; ks < 9; ++ks)
        #pragma unroll
        for (int g = 0; g < 3; ++g) {
            bw[ks][g] = *(const short8*)(wp +
                ((size_t)(ks * 4 + qq) * G3 + g * UNITS + u) * 8);
            asm("" : "+v"(bw[ks][g]));
        }

    // ---- init A[0]: h=0 everywhere, then x_0 ----
    for (int i = tid; i < MROWS * AP; i += 256)
        ((unsigned short*)&A_s[0][0][0])[i] = 0;
    __syncthreads();

    const int xrow = tid >> 4;             // 0..15
    const int xf0  = (tid & 15) * 2;       // 0,2,..,30
    {
        const float* xp = x_dyn + ((size_t)(b0 + xrow) * T_STEPS + 0) * 32 + xf0;
        A_s[0][xrow][UNITS + xf0]     = f2bf(xp[0]);
        A_s[0][xrow][UNITS + xf0 + 1] = f2bf(xp[1]);
    }
    float xr0 = 0.f, xr1 = 0.f;
    {
        const float* xp = x_dyn + ((size_t)(b0 + xrow) * T_STEPS + 1) * 32 + xf0;
        xr0 = xp[0]; xr1 = xp[1];
    }

    // ---- per-lane cell state: unit u, rows qq*4+r ----
    const float bf_ = bias[u], bo_ = bias[UNITS + u], bg_ = bias[2 * UNITS + u];
    float ig[4], cc[4], hp[4];
    #pragma unroll
    for (int r = 0; r < 4; ++r) {
        const int row = qq * 4 + r;
        float s = bias_s[u];
        #pragma unroll
        for (int j = 0; j < 27; ++j)
            s += x_sta[(b0 + row) * 27 + j] * w_sh[j * UNITS + u];
        ig[r] = sigmoidf_(s);
        cc[r] = 0.0f; hp[r] = 0.0f;
    }
    __syncthreads();   // A[0] fully staged

    int p = 0;
    for (int t = 0; t < T_STEPS; ++t) {
        // ---- gates for my 16 units x 16 rows ----
        short8 a[9];
        #pragma unroll
        for (int ks = 0; ks < 9; ++ks)
            a[ks] = *(const short8*)&A_s[p][mm][ks * 32 + qq * 8];

        f32x4 acF = {0.f,0.f,0.f,0.f}, acO = {0.f,0.f,0.f,0.f}, acG = {0.f,0.f,0.f,0.f};
        #pragma unroll
        for (int ks = 0; ks < 9; ++ks) {
            acF = __builtin_amdgcn_mfma_f32_16x16x32_bf16(a[ks], bw[ks][0], acF, 0, 0, 0);
            acO = __builtin_amdgcn_mfma_f32_16x16x32_bf16(a[ks], bw[ks][1], acO, 0, 0, 0);
            acG = __builtin_amdgcn_mfma_f32_16x16x32_bf16(a[ks], bw[ks][2], acG, 0, 0, 0);
        }

        // ---- cell update, all in registers ----
        #pragma unroll
        for (int r = 0; r < 4; ++r) {
            const float h0 = hp[r];                       // exact fp32 identity term
            const float f  = sigmoidf_(acF[r] + bf_ + h0);
            const float o  = sigmoidf_(acO[r] + bo_ + h0);
            const float g  = tanhf_  (acG[r] + bg_ + h0);
            const float cn = f * cc[r] + ig[r] * g;
            cc[r] = cn;
            hp[r] = o * tanhf_(cn);
        }

        if (t + 1 < T_STEPS) {
            const int np  = p ^ 1;
            const int par = (t + 1) & 1;

            // own h slice -> exchange (2 packed dwords) + local A[np]
            const unsigned d0 = (unsigned)f2bf(hp[0]) | ((unsigned)f2bf(hp[1]) << 16);
            const unsigned d1 = (unsigned)f2bf(hp[2]) | ((unsigned)f2bf(hp[3]) << 16);
            const int ebase = (((par * NGRP + grp) * 4 + sl) * 512) + (wv * 16 + mm) * 8 + qq * 2;
            __hip_atomic_store(&exch[ebase],     d0, __ATOMIC_RELAXED, __HIP_MEMORY_SCOPE_AGENT);
            __hip_atomic_store(&exch[ebase + 1], d1, __ATOMIC_RELAXED, __HIP_MEMORY_SCOPE_AGENT);
            #pragma unroll
            for (int r = 0; r < 4; ++r)
                A_s[np][qq * 4 + r][u] = f2bf(hp[r]);

            // stage x_{t+1}; prefetch x_{t+2}
            A_s[np][xrow][UNITS + xf0]     = f2bf(xr0);
            A_s[np][xrow][UNITS + xf0 + 1] = f2bf(xr1);
            if (t + 2 < T_STEPS) {
                const float* xp = x_dyn + ((size_t)(b0 + xrow) * T_STEPS + (t + 2)) * 32 + xf0;
                xr0 = xp[0]; xr1 = xp[1];
            }

            __threadfence();   // each thread's exch stores performed agent-wide
            __syncthreads();
            if (tid == 0)
                __hip_atomic_fetch_add(&cnt[grp], 1u, __ATOMIC_RELEASE, __HIP_MEMORY_SCOPE_AGENT);
            if (tid == 0) {
                const unsigned target = 4u * (unsigned)(t + 1);
                while (__hip_atomic_load(&cnt[grp], __ATOMIC_ACQUIRE, __HIP_MEMORY_SCOPE_AGENT) < target)
                    __builtin_amdgcn_s_sleep(1);
            }
            __syncthreads();

            // read 3 partner slices into A[np]
            #pragma unroll
            for (int pp = 1; pp < 4; ++pp) {
                const int sp = (sl + pp) & 3;
                const int pbase = ((par * NGRP + grp) * 4 + sp) * 512;
                #pragma unroll
                for (int half = 0; half < 2; ++half) {
                    const int d  = tid + half * 256;
                    const unsigned v = __hip_atomic_load(&exch[pbase + d],
                                        __ATOMIC_RELAXED, __HIP_MEMORY_SCOPE_AGENT);
                    const int lu = d >> 3, j = d & 7;
                    const int u2 = sp * 64 + lu;
                    A_s[np][2 * j][u2]     = (unsigned short)(v & 0xffffu);
                    A_s[np][2 * j + 1][u2] = (unsigned short)(v >> 16);
                }
            }
            __syncthreads();   // A[np] complete for next iteration
        }
        p ^= 1;
    }

    #pragma unroll
    for (int r = 0; r < 4; ++r)
        out[(size_t)(b0 + qq * 4 + r) * UNITS + u] = hp[r];
}

extern "C" void kernel_launch(void* const* d_in, const int* in_sizes, int n_in,
                              void* d_out, int out_size, void* d_ws, size_t ws_size,
                              hipStream_t stream) {
    const float* x_dyn  = (const float*)d_in[0];
    const float* x_sta  = (const float*)d_in[1];
    const float* w_ih   = (const float*)d_in[2];
    const float* w_hh   = (const float*)d_in[3];
    const float* w_sh   = (const float*)d_in[4];
    const float* bias   = (const float*)d_in[5];
    const float* bias_s = (const float*)d_in[6];
    float* out = (float*)d_out;

    unsigned short* wp  = (unsigned short*)d_ws;
    unsigned int*   cnt = (unsigned int*)((char*)d_ws + CNT_OFF);
    unsigned int*   ex  = (unsigned int*)((char*)d_ws + EXCH_OFF);

    hipMemsetAsync(cnt, 0, NGRP * sizeof(unsigned int), stream);
    pack_weights<<<(KTOT * G3 + 255) / 256, 256, 0, stream>>>(w_ih, w_hh, wp);
    lstm_nsplit<<<256, 256, 0, stream>>>(x_dyn, x_sta, wp, w_sh, bias, bias_s,
                                         cnt, ex, out);
}

// Round 7
// 1659.225 us; speedup vs baseline: 5.5966x; 5.5966x over previous
//
#include <hip/hip_runtime.h>
#include <hip/hip_bf16.h>

// EntityAwareLSTMLayer: B=1024, T=365, DYN=32, STATIC=27, U=256 (3U=768)
// Round 7: single-WG-per-CU, 1 wave/SIMD, weights truly resident.
//   - 64 WGs x 256 thr (4 waves, 1/SIMD -> 512-reg budget, launch_bounds(256,1)).
//     Round 6 proved asm("+v") pinning holds at this occupancy.
//   - Wave wv owns units wv*64..+63 (4 unit-groups of 16) x 3 gates.
//     W_hh-residual kchunks 0..6: 84 B-frags = 336 pinned VGPRs/wave.
//     kchunks 7..8 (last W_hh rows + W_ih) in LDS (96 KB). No global weight
//     traffic in the t-loop.
//   - M=16: full C-tiles, cell state (cc/hp fp32 + ig + biases) in registers,
//     no shuffles, ONE __syncthreads per step.
//   - Step software-pipelined by unit-group: GROUP(ug+1) MFMAs issue before
//     CELL(ug) so transcendentals run in the matrix-pipe shadow.
//   - MFMA-issue floor: 2098 cyc/CU/step on 64 CUs -> ~319 us structural.

typedef short short8 __attribute__((ext_vector_type(8)));
typedef float f32x4 __attribute__((ext_vector_type(4)));

#define T_STEPS 365
#define UNITS   256
#define G3      768
#define KTOT    288
#define MROWS   16
#define AP      296   // padded A row length in shorts

__device__ __forceinline__ unsigned short f2bf(float x) {
    union { float f; unsigned u; } v; v.f = x;
    return (unsigned short)((v.u + 0x7FFFu + ((v.u >> 16) & 1u)) >> 16);
}
__device__ __forceinline__ float sigmoidf_(float x) {
    return 1.0f / (1.0f + __expf(-x));
}
__device__ __forceinline__ float tanhf_(float x) {
    return 1.0f - 2.0f / (1.0f + __expf(2.0f * x));
}

// Wpack[k=0..287][n=0..767] -> bf16 B-frag layout: wp[((k>>3)*768 + n)*8 + (k&7)]
__global__ __launch_bounds__(256) void pack_weights(
    const float* __restrict__ w_ih, const float* __restrict__ w_hh,
    unsigned short* __restrict__ wp)
{
    int idx = blockIdx.x * 256 + threadIdx.x;
    if (idx >= KTOT * G3) return;
    int k = idx / G3, n = idx - k * G3;
    float v;
    if (k < UNITS) {
        v = w_hh[k * G3 + n];
        if ((n & 255) == k) v -= 1.0f;   // subtract eye3 tile
    } else {
        v = w_ih[(k - UNITS) * G3 + n];
    }
    wp[(((k >> 3) * G3) + n) * 8 + (k & 7)] = f2bf(v);
}

#define MFMA(acc, av, bv) \
    acc = __builtin_amdgcn_mfma_f32_16x16x32_bf16(av, bv, acc, 0, 0, 0)

// 27 MFMAs for unit-group ug into (F,O,Gc): kchunks 0..6 from regs, 7..8 from LDS
#define GROUP(ug, F, O, Gc) do {                                              \
    const unsigned short* Ab_ = &A_s[p][mm][0];                               \
    F = (f32x4){0.f,0.f,0.f,0.f}; O = (f32x4){0.f,0.f,0.f,0.f};               \
    Gc = (f32x4){0.f,0.f,0.f,0.f};                                            \
    _Pragma("unroll")                                                         \
    for (int ks = 0; ks < 7; ++ks) {                                          \
        const short8 a = *(const short8*)(Ab_ + ks * 32 + qq * 8);            \
        MFMA(F, a, bw[ks][0][ug]); MFMA(O, a, bw[ks][1][ug]);                 \
        MFMA(Gc, a, bw[ks][2][ug]);                                           \
    }                                                                         \
    _Pragma("unroll")                                                         \
    for (int d = 0; d < 2; ++d) {                                             \
        const short8 a = *(const short8*)(Ab_ + (7 + d) * 32 + qq * 8);       \
        const int nb_ = wv * 64 + (ug) * 16 + mm;                             \
        const short8 bF_ = *(const short8*)&B_s[d][qq][nb_][0];               \
        const short8 bO_ = *(const short8*)&B_s[d][qq][256 + nb_][0];         \
        const short8 bG_ = *(const short8*)&B_s[d][qq][512 + nb_][0];         \
        MFMA(F, a, bF_); MFMA(O, a, bO_); MFMA(Gc, a, bG_);                   \
    }                                                                         \
} while (0)

// cell update for unit-group ug's 4 rows; writes h_{t+1} bf16 into A[np]
#define CELL(ug, F, O, Gc) do {                                               \
    const int ub_ = wv * 64 + (ug) * 16 + mm;                                 \
    _Pragma("unroll")                                                         \
    for (int r = 0; r < 4; ++r) {                                             \
        const int ci = (ug) * 4 + r;                                          \
        const float h0 = hp[ci];             /* exact fp32 identity term */   \
        const float fv = sigmoidf_(F[r]  + bFv[ug] + h0);                     \
        const float ov = sigmoidf_(O[r]  + bOv[ug] + h0);                     \
        const float gv = tanhf_  (Gc[r] + bGv[ug] + h0);                      \
        const float cn = fv * cc[ci] + ig[ci] * gv;                           \
        cc[ci] = cn;                                                          \
        const float hn = ov * tanhf_(cn);                                     \
        hp[ci] = hn;                                                          \
        A_s[np][qq * 4 + r][ub_] = f2bf(hn);                                  \
    }                                                                         \
} while (0)

__global__ __launch_bounds__(256, 1) void lstm_regres(
    const float* __restrict__ x_dyn,   // [1024][365][32]
    const float* __restrict__ x_sta,   // [1024][27]
    const unsigned short* __restrict__ wp,
    const float* __restrict__ w_sh,    // [27][256]
    const float* __restrict__ bias,    // [768]
    const float* __restrict__ bias_s,  // [256]
    float* __restrict__ out)           // [1024][256]
{
    __shared__ unsigned short A_s[2][MROWS][AP];      // 18.5 KB
    __shared__ unsigned short B_s[2][4][G3][8];       // 96 KB: kchunks 7..8

    const int tid  = threadIdx.x;
    const int b0   = blockIdx.x * MROWS;
    const int lane = tid & 63;
    const int wv   = tid >> 6;           // wave 0..3: units wv*64..+63
    const int mm   = lane & 15;
    const int qq   = lane >> 4;

    // ---- 84 B-fragments (7 kchunks x 3 gates x 4 unit-groups), pinned ----
    short8 bw[7][3][4];
    #pragma unroll
    for (int ks = 0; ks < 7; ++ks)
        #pragma unroll
        for (int g = 0; g < 3; ++g)
            #pragma unroll
            for (int ug = 0; ug < 4; ++ug) {
                bw[ks][g][ug] = *(const short8*)(wp +
                    ((size_t)(ks * 4 + qq) * G3 + g * UNITS + wv * 64 + ug * 16 + mm) * 8);
                asm("" : "+v"(bw[ks][g][ug]));
            }

    // ---- kchunks 7..8 -> LDS (6144 short8 elements) ----
    {
        const short8* src = (const short8*)(wp + (size_t)28 * G3 * 8);
        short8* dst = (short8*)&B_s[0][0][0][0];
        for (int i = tid; i < 2 * 4 * G3; i += 256) dst[i] = src[i];
    }

    // ---- init A[0]: zero h region, stage x_0, prefetch x_1 ----
    for (int i = tid; i < MROWS * AP; i += 256)
        ((unsigned short*)&A_s[0][0][0])[i] = 0;
    __syncthreads();   // zeros done before x staging into same buffer

    const int xrow = tid >> 4;           // 0..15
    const int xf0  = (tid & 15) * 2;     // 0,2,..,30
    {
        const float* xp = x_dyn + ((size_t)(b0 + xrow) * T_STEPS + 0) * 32 + xf0;
        A_s[0][xrow][UNITS + xf0]     = f2bf(xp[0]);
        A_s[0][xrow][UNITS + xf0 + 1] = f2bf(xp[1]);
    }
    float xr0, xr1;
    {
        const float* xp = x_dyn + ((size_t)(b0 + xrow) * T_STEPS + 1) * 32 + xf0;
        xr0 = xp[0]; xr1 = xp[1];
    }

    // ---- per-lane cell state: 16 cells = 4 unit-groups x 4 rows ----
    float bFv[4], bOv[4], bGv[4], ig[16], cc[16], hp[16];
    #pragma unroll
    for (int ug = 0; ug < 4; ++ug) {
        const int u = wv * 64 + ug * 16 + mm;
        bFv[ug] = bias[u];
        bOv[ug] = bias[UNITS + u];
        bGv[ug] = bias[2 * UNITS + u];
        #pragma unroll
        for (int r = 0; r < 4; ++r) {
            const int row = qq * 4 + r;
            float s = bias_s[u];
            #pragma unroll
            for (int j = 0; j < 27; ++j)
                s += x_sta[(b0 + row) * 27 + j] * w_sh[j * UNITS + u];
            ig[ug * 4 + r] = sigmoidf_(s);
            cc[ug * 4 + r] = 0.0f;
            hp[ug * 4 + r] = 0.0f;
        }
    }

    int p = 0;
    for (int t = 0; t < T_STEPS; ++t) {
        __syncthreads();   // A[p] = [h_t | x_t] complete; A[np] free
        const int np = p ^ 1;

        f32x4 F0, O0, G0, F1, O1, G1;
        // software pipeline: GROUP(ug+1) issues before CELL(ug) so the
        // matrix pipe stays busy while transcendentals run in its shadow.
        GROUP(0, F0, O0, G0);
        GROUP(1, F1, O1, G1);
        CELL (0, F0, O0, G0);
        GROUP(2, F0, O0, G0);
        CELL (1, F1, O1, G1);
        GROUP(3, F1, O1, G1);
        CELL (2, F0, O0, G0);
        CELL (3, F1, O1, G1);

        // stage x_{t+1} into A[np]; prefetch x_{t+2}
        if (t + 1 < T_STEPS) {
            A_s[np][xrow][UNITS + xf0]     = f2bf(xr0);
            A_s[np][xrow][UNITS + xf0 + 1] = f2bf(xr1);
            if (t + 2 < T_STEPS) {
                const float* xp = x_dyn + ((size_t)(b0 + xrow) * T_STEPS + (t + 2)) * 32 + xf0;
                xr0 = xp[0]; xr1 = xp[1];
            }
        }
        p = np;
    }

    #pragma unroll
    for (int ug = 0; ug < 4; ++ug)
        #pragma unroll
        for (int r = 0; r < 4; ++r)
            out[(size_t)(b0 + qq * 4 + r) * UNITS + wv * 64 + ug * 16 + mm] =
                hp[ug * 4 + r];
}

extern "C" void kernel_launch(void* const* d_in, const int* in_sizes, int n_in,
                              void* d_out, int out_size, void* d_ws, size_t ws_size,
                              hipStream_t stream) {
    const float* x_dyn  = (const float*)d_in[0];
    const float* x_sta  = (const float*)d_in[1];
    const float* w_ih   = (const float*)d_in[2];
    const float* w_hh   = (const float*)d_in[3];
    const float* w_sh   = (const float*)d_in[4];
    const float* bias   = (const float*)d_in[5];
    const float* bias_s = (const float*)d_in[6];
    float* out = (float*)d_out;
    unsigned short* wp = (unsigned short*)d_ws;   // 288*768*2 = 442 KB scratch

    pack_weights<<<(KTOT * G3 + 255) / 256, 256, 0, stream>>>(w_ih, w_hh, wp);
    lstm_regres<<<64, 256, 0, stream>>>(x_dyn, x_sta, wp, w_sh, bias, bias_s, out);
}